// Round 2
// baseline (444.877 us; speedup 1.0000x reference)
//
#include <hip/hip_runtime.h>
#include <hip/hip_bf16.h>

#define NN 262144
#define DD 256
#define HH 128
#define GG 2048
#define LW1 264   // padded LDS row stride for W1T (bf16 units): 264*2=528 B, 16B-aligned, breaks pow2 banks

typedef __attribute__((ext_vector_type(8))) __bf16 bf16x8;
typedef __attribute__((ext_vector_type(4))) float f32x4;

union ABFrag { bf16x8 v; unsigned short u[8]; uint4 i; };

__device__ __forceinline__ unsigned short f2bf(float f) {
    unsigned int u = __float_as_uint(f);
    return (unsigned short)((u + 0x7fffu + ((u >> 16) & 1u)) >> 16);
}

// ---------------- kernel 0: W1 (fp32 [256][128]) -> W1T (bf16 [128][256]) ----
__global__ void prep_kernel(const float* __restrict__ w1, unsigned short* __restrict__ w1t) {
    int i = blockIdx.x * 256 + threadIdx.x;
    int n = i >> 8;     // W1T row (hidden dim)
    int k = i & 255;    // W1T col (input dim)
    w1t[i] = f2bf(w1[k * HH + n]);
}

// ---------------- kernel 1: segment bounds (bnd[g] = first index with batch>=g)
__global__ void bounds_kernel(const int* __restrict__ batch, int* __restrict__ bnd) {
    int g = blockIdx.x * 256 + threadIdx.x;   // need 0..GG inclusive
    if (g > GG) return;
    int lo = 0, hi = NN;
    while (lo < hi) { int mid = (lo + hi) >> 1; if (batch[mid] < g) lo = mid + 1; else hi = mid; }
    bnd[g] = lo;
}

// ---------------- kernel 2: fused scores + online softmax + weighted pooling --
// One block (256 thr = 4 waves) per graph. Stream segment in 64-row chunks:
//   phase A: wave w MFMA-scores rows [base+16w, base+16w+16)  (W1T from LDS)
//   phase B: wave 0 updates running (m,l), emits e_i + rescale alpha
//   phase C: all threads: acc[d] = acc[d]*alpha + sum_i e_i * x[base+i][d]
//            (x rows are L2-hot: fetched by phase A on the same CU)
__global__ __launch_bounds__(256, 2)
void fused_kernel(const float* __restrict__ x,
                  const unsigned short* __restrict__ w1t,
                  const float* __restrict__ b1,
                  const float* __restrict__ w2,
                  const int* __restrict__ bnd,
                  float* __restrict__ out)
{
    __shared__ __align__(16) unsigned short w1s[HH * LW1];
    __shared__ float s_lds[64];
    __shared__ float e_lds[64];
    __shared__ float bc[2];   // bc[0]=alpha for this chunk, bc[1]=final l

    const int g = blockIdx.x;
    const int tid = threadIdx.x;
    const int lane = tid & 63;
    const int wv = tid >> 6;
    const int c = lane & 15;
    const int q = lane >> 4;

    const int start = bnd[g];
    const int end = bnd[g + 1];

    // stage W1T -> LDS (coalesced global read, padded-stride LDS write)
#pragma unroll
    for (int k = 0; k < 16; ++k) {
        int idx = tid + k * 256;            // uint4 index 0..4095 (64 KB)
        int r = idx >> 5;                    // row 0..127
        int col = (idx & 31) * 8;            // bf16 col 0..248
        *(uint4*)&w1s[r * LW1 + col] = ((const uint4*)w1t)[idx];
    }

    float b1v[8], w2v[8];
#pragma unroll
    for (int t = 0; t < 8; ++t) { b1v[t] = b1[t * 16 + c]; w2v[t] = w2[t * 16 + c]; }

    __syncthreads();

    float acc = 0.f;               // my column (d = tid) of the pooled output
    float m = -3.402823466e38f;    // running max   (wave 0 lane-uniform)
    float l = 0.f;                 // running sum   (wave 0 lane-uniform)

    for (int base = start; base < end; base += 64) {
        // ---- phase A: MFMA scores for my wave's 16 rows ----
        f32x4 accs[8];
#pragma unroll
        for (int t = 0; t < 8; ++t) accs[t] = (f32x4){0.f, 0.f, 0.f, 0.f};

        const int row = base + wv * 16 + c;
        const bool valid = row < end;
        const float* px = x + (size_t)row * DD;

#pragma unroll
        for (int kk = 0; kk < 8; ++kk) {
            ABFrag af;
            if (valid) {
                float4 f0 = *(const float4*)(px + kk * 32 + q * 8);
                float4 f1 = *(const float4*)(px + kk * 32 + q * 8 + 4);
                af.u[0] = f2bf(f0.x); af.u[1] = f2bf(f0.y); af.u[2] = f2bf(f0.z); af.u[3] = f2bf(f0.w);
                af.u[4] = f2bf(f1.x); af.u[5] = f2bf(f1.y); af.u[6] = f2bf(f1.z); af.u[7] = f2bf(f1.w);
            } else {
                af.i = (uint4){0u, 0u, 0u, 0u};
            }
#pragma unroll
            for (int t = 0; t < 8; ++t) {
                ABFrag bf;
                bf.i = *(const uint4*)&w1s[(t * 16 + c) * LW1 + kk * 32 + q * 8];
                accs[t] = __builtin_amdgcn_mfma_f32_16x16x32_bf16(af.v, bf.v, accs[t], 0, 0, 0);
            }
        }

        // epilogue: +b1, relu, *W2, reduce the 128 hidden dims (b2 cancels in softmax)
        float s0 = 0.f, s1 = 0.f, s2 = 0.f, s3 = 0.f;
#pragma unroll
        for (int t = 0; t < 8; ++t) {
            float w = w2v[t], bb = b1v[t];
            f32x4 a = accs[t];
            s0 += fmaxf(a.x + bb, 0.f) * w;
            s1 += fmaxf(a.y + bb, 0.f) * w;
            s2 += fmaxf(a.z + bb, 0.f) * w;
            s3 += fmaxf(a.w + bb, 0.f) * w;
        }
#pragma unroll
        for (int off = 1; off < 16; off <<= 1) {
            s0 += __shfl_xor(s0, off);
            s1 += __shfl_xor(s1, off);
            s2 += __shfl_xor(s2, off);
            s3 += __shfl_xor(s3, off);
        }
        if (c == 0) {
            float* o = s_lds + wv * 16 + q * 4;
            o[0] = s0; o[1] = s1; o[2] = s2; o[3] = s3;
        }
        __syncthreads();

        // ---- phase B: online softmax state (wave 0) ----
        if (wv == 0) {
            const int n = min(64, end - base);
            float s = (lane < n) ? s_lds[lane] : -3.402823466e38f;
            float cmax = s;
#pragma unroll
            for (int off = 1; off < 64; off <<= 1) cmax = fmaxf(cmax, __shfl_xor(cmax, off));
            float newm = fmaxf(m, cmax);
            float alpha = __expf(m - newm);          // 0 on first chunk (m=-inf)
            float e = (lane < n) ? __expf(s - newm) : 0.f;
            float es = e;
#pragma unroll
            for (int off = 1; off < 64; off <<= 1) es += __shfl_xor(es, off);
            l = l * alpha + es;
            m = newm;
            e_lds[lane] = e;
            if (lane == 0) bc[0] = alpha;
        }
        __syncthreads();

        // ---- phase C: rescale + weighted accumulate (L2-hot re-read) ----
        const float alpha = bc[0];
        acc *= alpha;
        const int nn = min(64, NN - base);           // rows safe to address
        const float* pxp = x + (size_t)base * DD + tid;
#pragma unroll 8
        for (int i = 0; i < nn; ++i) {
            acc = fmaf(e_lds[i], pxp[(size_t)i * DD], acc);
        }
        __syncthreads();   // protect s_lds/e_lds before next chunk overwrites
    }

    if (wv == 0 && lane == 0) bc[1] = l;
    __syncthreads();
    const float L = bc[1];
    out[(size_t)g * DD + tid] = (L > 0.f) ? acc / L : 0.f;
}

extern "C" void kernel_launch(void* const* d_in, const int* in_sizes, int n_in,
                              void* d_out, int out_size, void* d_ws, size_t ws_size,
                              hipStream_t stream) {
    const float* x     = (const float*)d_in[0];
    const int*   batch = (const int*)d_in[1];
    const float* W1    = (const float*)d_in[3];
    const float* b1    = (const float*)d_in[4];
    const float* W2    = (const float*)d_in[5];
    float* out = (float*)d_out;

    char* ws = (char*)d_ws;
    unsigned short* w1t = (unsigned short*)ws;                 // 32768 bf16 (64 KB)
    int*            bnd = (int*)(ws + 65536);                  // GG+1 ints

    prep_kernel<<<HH * DD / 256, 256, 0, stream>>>(W1, w1t);
    bounds_kernel<<<(GG + 1 + 255) / 256, 256, 0, stream>>>(batch, bnd);
    fused_kernel<<<GG, 256, 0, stream>>>(x, w1t, b1, W2, bnd, out);
}

// Round 3
// 422.645 us; speedup vs baseline: 1.0526x; 1.0526x over previous
//
#include <hip/hip_runtime.h>
#include <hip/hip_bf16.h>

#define NN 262144
#define DD 256
#define HH 128
#define GG 2048

typedef __attribute__((ext_vector_type(8))) __bf16 bf16x8;
typedef __attribute__((ext_vector_type(4))) float f32x4;

union ABFrag { bf16x8 v; unsigned short u[8]; uint4 i; };

__device__ __forceinline__ unsigned short f2bf(float f) {
    unsigned int u = __float_as_uint(f);
    return (unsigned short)((u + 0x7fffu + ((u >> 16) & 1u)) >> 16);
}

// ---------------- kernel 0: W1 (fp32 [256][128]) -> W1T (bf16 [128][256]) ----
__global__ void prep_kernel(const float* __restrict__ w1, unsigned short* __restrict__ w1t) {
    int i = blockIdx.x * 256 + threadIdx.x;
    int n = i >> 8;     // hidden dim
    int k = i & 255;    // input dim
    w1t[i] = f2bf(w1[k * HH + n]);
}

// ---------------- kernel 1: segment bounds ----------------------------------
__global__ void bounds_kernel(const int* __restrict__ batch, int* __restrict__ bnd) {
    int g = blockIdx.x * 256 + threadIdx.x;   // 0..GG inclusive
    if (g > GG) return;
    int lo = 0, hi = NN;
    while (lo < hi) { int mid = (lo + hi) >> 1; if (batch[mid] < g) lo = mid + 1; else hi = mid; }
    bnd[g] = lo;
}

// ---------------- kernel 2: fused scores + online softmax + pooling ----------
// One block (4 waves) per graph; 64-row chunks.
//  stage : 64 rows x -> LDS bf16, XOR-swizzled (conflict-free write & read)
//  mfma  : wave w holds B-frags for hidden tiles {2w,2w+1} in regs; computes
//          partial scores for ALL 64 rows; partials -> part[4][64] in LDS
//  phase B: wave 0 combines partials, online-softmax update, e_lds + alpha
//  phase C: float4 weighted accumulation (global fp32 re-read, L2-hot)
__global__ __launch_bounds__(256, 3)
void fused_kernel(const float* __restrict__ x,
                  const unsigned short* __restrict__ w1t,
                  const float* __restrict__ b1,
                  const float* __restrict__ w2,
                  const int* __restrict__ bnd,
                  float* __restrict__ out)
{
    __shared__ __align__(16) unsigned short xs[64 * DD];   // 32 KB
    __shared__ float part[4 * 64];                          // 1 KB
    __shared__ float e_lds[64];
    __shared__ float bcast[1];

    const int g = blockIdx.x;
    const int tid = threadIdx.x;
    const int lane = tid & 63;
    const int wv = tid >> 6;
    const int c = lane & 15;
    const int q = lane >> 4;

    const int start = bnd[g];
    const int end = bnd[g + 1];

    // persistent B-frags: this wave's 2 hidden tiles, all 8 K-steps (64 VGPRs)
    ABFrag bfr[2][8];
#pragma unroll
    for (int j = 0; j < 2; ++j)
#pragma unroll
        for (int kk = 0; kk < 8; ++kk)
            bfr[j][kk].i = *(const uint4*)(w1t + (size_t)((2 * wv + j) * 16 + c) * DD + kk * 32 + q * 8);

    float b1v[2], w2v[2];
#pragma unroll
    for (int j = 0; j < 2; ++j) {
        b1v[j] = b1[(2 * wv + j) * 16 + c];
        w2v[j] = w2[(2 * wv + j) * 16 + c];
    }

    float4 acc4 = {0.f, 0.f, 0.f, 0.f};     // my 4 output cols: [lane*4, lane*4+4)
    float m = -3.402823466e38f;              // running max (wave 0)
    float l = 0.f;                           // running sum (wave 0)

    for (int base = start; base < end; base += 64) {
        const int n = min(64, end - base);

        // ---- stage: 64 rows -> LDS bf16, swizzled ----
#pragma unroll
        for (int jj = 0; jj < 8; ++jj) {
            int id = jj * 256 + tid;
            int row = id >> 5;               // 0..63
            int blk = id & 31;               // 16B block within row
            ABFrag af;
            if (row < n) {
                const float4* p4 = (const float4*)(x + (size_t)(base + row) * DD + blk * 8);
                float4 f0 = p4[0], f1 = p4[1];
                af.u[0] = f2bf(f0.x); af.u[1] = f2bf(f0.y); af.u[2] = f2bf(f0.z); af.u[3] = f2bf(f0.w);
                af.u[4] = f2bf(f1.x); af.u[5] = f2bf(f1.y); af.u[6] = f2bf(f1.z); af.u[7] = f2bf(f1.w);
            } else {
                af.i = (uint4){0u, 0u, 0u, 0u};
            }
            *(uint4*)&xs[row * DD + (((blk ^ (row & 7)) ) << 3)] = af.i;
        }
        __syncthreads();

        // ---- mfma: 4 m-tiles x 2 t-tiles ----
        f32x4 accs[4][2];
#pragma unroll
        for (int mt = 0; mt < 4; ++mt)
#pragma unroll
            for (int j = 0; j < 2; ++j) accs[mt][j] = (f32x4){0.f, 0.f, 0.f, 0.f};

#pragma unroll
        for (int kk = 0; kk < 8; ++kk) {
            ABFrag af[4];
#pragma unroll
            for (int mt = 0; mt < 4; ++mt) {
                int row = mt * 16 + c;
                af[mt].i = *(const uint4*)&xs[row * DD + ((((kk * 4 + q) ^ (c & 7))) << 3)];
            }
#pragma unroll
            for (int mt = 0; mt < 4; ++mt)
#pragma unroll
                for (int j = 0; j < 2; ++j)
                    accs[mt][j] = __builtin_amdgcn_mfma_f32_16x16x32_bf16(af[mt].v, bfr[j][kk].v, accs[mt][j], 0, 0, 0);
        }

        // epilogue: +b1, relu, *w2, reduce my 32 hidden dims -> partial scores
#pragma unroll
        for (int mt = 0; mt < 4; ++mt) {
            float s0 = 0.f, s1 = 0.f, s2 = 0.f, s3 = 0.f;
#pragma unroll
            for (int j = 0; j < 2; ++j) {
                float w = w2v[j], bb = b1v[j];
                f32x4 a = accs[mt][j];
                s0 += fmaxf(a.x + bb, 0.f) * w;
                s1 += fmaxf(a.y + bb, 0.f) * w;
                s2 += fmaxf(a.z + bb, 0.f) * w;
                s3 += fmaxf(a.w + bb, 0.f) * w;
            }
#pragma unroll
            for (int off = 1; off < 16; off <<= 1) {
                s0 += __shfl_xor(s0, off);
                s1 += __shfl_xor(s1, off);
                s2 += __shfl_xor(s2, off);
                s3 += __shfl_xor(s3, off);
            }
            if (c == 0) {
                float* o = part + wv * 64 + mt * 16 + q * 4;
                o[0] = s0; o[1] = s1; o[2] = s2; o[3] = s3;
            }
        }
        __syncthreads();

        // ---- phase B: combine partials + online softmax (wave 0) ----
        if (wv == 0) {
            float s = (lane < n)
                ? (part[lane] + part[64 + lane] + part[128 + lane] + part[192 + lane])
                : -3.402823466e38f;
            float cmax = s;
#pragma unroll
            for (int off = 1; off < 64; off <<= 1) cmax = fmaxf(cmax, __shfl_xor(cmax, off));
            float newm = fmaxf(m, cmax);
            float alpha = (m > -1.0e37f) ? __expf(m - newm) : 0.f;
            float e = (lane < n) ? __expf(s - newm) : 0.f;
            float es = e;
#pragma unroll
            for (int off = 1; off < 64; off <<= 1) es += __shfl_xor(es, off);
            l = l * alpha + es;
            m = newm;
            e_lds[lane] = e;
            if (lane == 0) bcast[0] = alpha;
        }
        __syncthreads();

        // ---- phase C: rescale + float4 weighted accumulation ----
        const float alpha = bcast[0];
        acc4.x *= alpha; acc4.y *= alpha; acc4.z *= alpha; acc4.w *= alpha;
#pragma unroll 4
        for (int i = wv; i < n; i += 4) {
            float w = e_lds[i];
            float4 xv = ((const float4*)(x + (size_t)(base + i) * DD))[lane];
            acc4.x = fmaf(w, xv.x, acc4.x);
            acc4.y = fmaf(w, xv.y, acc4.y);
            acc4.z = fmaf(w, xv.z, acc4.z);
            acc4.w = fmaf(w, xv.w, acc4.w);
        }
        // no barrier needed: next stage's xs writes are fenced by this chunk's
        // post-mfma barrier; e_lds/part next writes are fenced by next barriers
    }

    // ---- final: cross-wave reduction of acc4, divide by l, store ----
    float4* arr = (float4*)xs;       // reuse stage buffer (all MFMA reads fenced)
    arr[wv * 64 + lane] = acc4;
    __syncthreads();
    if (wv == 0) {
        float4 a0 = arr[lane], a1 = arr[64 + lane], a2 = arr[128 + lane], a3 = arr[192 + lane];
        float inv = (l > 0.f) ? 1.f / l : 0.f;
        float4 o;
        o.x = (a0.x + a1.x + a2.x + a3.x) * inv;
        o.y = (a0.y + a1.y + a2.y + a3.y) * inv;
        o.z = (a0.z + a1.z + a2.z + a3.z) * inv;
        o.w = (a0.w + a1.w + a2.w + a3.w) * inv;
        ((float4*)out)[(size_t)g * 64 + lane] = o;
    }
}

extern "C" void kernel_launch(void* const* d_in, const int* in_sizes, int n_in,
                              void* d_out, int out_size, void* d_ws, size_t ws_size,
                              hipStream_t stream) {
    const float* x     = (const float*)d_in[0];
    const int*   batch = (const int*)d_in[1];
    const float* W1    = (const float*)d_in[3];
    const float* b1    = (const float*)d_in[4];
    const float* W2    = (const float*)d_in[5];
    float* out = (float*)d_out;

    char* ws = (char*)d_ws;
    unsigned short* w1t = (unsigned short*)ws;                 // 32768 bf16 (64 KB)
    int*            bnd = (int*)(ws + 65536);                  // GG+1 ints

    prep_kernel<<<HH * DD / 256, 256, 0, stream>>>(W1, w1t);
    bounds_kernel<<<(GG + 1 + 255) / 256, 256, 0, stream>>>(batch, bnd);
    fused_kernel<<<GG, 256, 0, stream>>>(x, w1t, b1, W2, bnd, out);
}